// Round 2
// baseline (315.115 us; speedup 1.0000x reference)
//
#include <hip/hip_runtime.h>
#include <hip/hip_bf16.h>

// Problem: B=128, N=196, C=768, centers=64
//   q = mean_n x; attn = softmax(l2n(q)@l2n(k_c) * C^-0.5)
//   v = attn@v_c (B,N,N); out = (v @ x) @ W^T + b
// Reassociated: xp_t[b,d,m] = sum_k W[d,k] x[b,m,k]  (NT GEMM, output transposed)
//               out[b,n,d]  = sum_m v[b,n,m] xp_t[b,d,m] + bias[d] (NT GEMM)
// R5: both GEMMs rewritten as a 256x256-tile, 8-wave, phase-split pipelined kernel:
//   - BK=32, ring of 4 LDS slots (128 KB total). While computing tile t (2 phases,
//     16 MFMA each, per-phase s_barrier + s_setprio), tile t+3 is staged into slot
//     (t+3)%4 -- freed at tile t-1, so the global_load_lds destination is free at
//     issue time (provably race-free counted-vmcnt pipeline).
//   - one s_waitcnt vmcnt(8) per K-tile at the tile boundary (never 0 in the main
//     loop); tail drains 8 -> 4 -> 0. Loads span 3 tiles -> HBM latency hidden.
//   - T2 swizzle: 16B-chunk index XOR'd with (row>>2)&3 on the GLOBAL source side
//     (global_load_lds writes linearly), inverted on ds_read_b128 -> 2-way floor.
//   - K of gemm2 padded 224->256 (x_bf rows 196..255 zeroed so xp_t pad cols = 0).

#define NB   128
#define NN   196
#define NC   768
#define NCEN 64
#define RPAD 256   // padded row-dim for x_bf (m rows) and v_pad (n rows)
#define KPAD 256   // padded m index (K of gemm2, cols of xp_t)
#define BGRP 32    // batches per mix block
#define QPARTS 7

using bf16x8 = __attribute__((ext_vector_type(8))) short;
using f32x4  = __attribute__((ext_vector_type(4))) float;

__device__ __forceinline__ void async_copy16(const void* g, void* l) {
    // width=16: emits global_load_lds_dwordx4. LDS dest = wave-uniform base + lane*16.
    __builtin_amdgcn_global_load_lds((const __attribute__((address_space(1))) void*)g,
                                     (__attribute__((address_space(3))) void*)l, 16, 0, 0);
}

// ---- kernel 1: x -> bf16 (padded) + partial column sums; grid (NB, 7), block 192 ----
__global__ __launch_bounds__(192)
void convert_x_kernel(const float* __restrict__ x, __hip_bfloat16* __restrict__ x_bf,
                      float* __restrict__ q_part) {
    __shared__ float qsh[NC];
    int b = blockIdx.x, y = blockIdx.y, t = threadIdx.x;
    int cg = t % 96, rg = t / 96;
    int c = cg * 8;
    const float* xp = x + (size_t)b * NN * NC + c;
    __hip_bfloat16* xo = x_bf + (size_t)b * RPAD * NC + c;
    float s[8] = {0.f, 0.f, 0.f, 0.f, 0.f, 0.f, 0.f, 0.f};
    int m0 = y * 28 + rg * 14;
#pragma unroll 2
    for (int m = m0; m < m0 + 14; ++m) {
        const float* src = xp + (size_t)m * NC;
        float4 v0 = *(const float4*)src;
        float4 v1 = *(const float4*)(src + 4);
        union { bf16x8 v; __hip_bfloat16 h[8]; } u;
        u.h[0] = __float2bfloat16(v0.x); s[0] += v0.x;
        u.h[1] = __float2bfloat16(v0.y); s[1] += v0.y;
        u.h[2] = __float2bfloat16(v0.z); s[2] += v0.z;
        u.h[3] = __float2bfloat16(v0.w); s[3] += v0.w;
        u.h[4] = __float2bfloat16(v1.x); s[4] += v1.x;
        u.h[5] = __float2bfloat16(v1.y); s[5] += v1.y;
        u.h[6] = __float2bfloat16(v1.z); s[6] += v1.z;
        u.h[7] = __float2bfloat16(v1.w); s[7] += v1.w;
        *(bf16x8*)(xo + (size_t)m * NC) = u.v;
    }
    if (y == 6) {
        // zero rows 196..255: their xp_t columns feed gemm2's padded K range and
        // must be exact zeros (0 * 0, never NaN * 0).
        bf16x8 z = {};
        int mz0 = 196 + rg * 30;
        for (int m = mz0; m < mz0 + 30; ++m)
            *(bf16x8*)(xo + (size_t)m * NC) = z;
    }
    if (rg == 0) {
#pragma unroll
        for (int j = 0; j < 8; ++j) qsh[c + j] = s[j];
    }
    __syncthreads();
    if (rg == 1) {
        float* qp = q_part + ((size_t)y * NB + b) * NC + c;
        float4 o0 = make_float4(qsh[c] + s[0], qsh[c + 1] + s[1],
                                qsh[c + 2] + s[2], qsh[c + 3] + s[3]);
        float4 o1 = make_float4(qsh[c + 4] + s[4], qsh[c + 5] + s[5],
                                qsh[c + 6] + s[6], qsh[c + 7] + s[7]);
        *(float4*)qp = o0;
        *(float4*)(qp + 4) = o1;
    }
}

// ---------------- kernel 2: proj_w -> bf16 (vectorized) ----------------
__global__ __launch_bounds__(256)
void convert_w_kernel(const float* __restrict__ w, __hip_bfloat16* __restrict__ w_bf) {
    int i = (blockIdx.x * 256 + threadIdx.x) * 8;
    if (i >= NC * NC) return;
    float4 v0 = *(const float4*)(w + i);
    float4 v1 = *(const float4*)(w + i + 4);
    union { bf16x8 v; __hip_bfloat16 h[8]; } u;
    u.h[0] = __float2bfloat16(v0.x);
    u.h[1] = __float2bfloat16(v0.y);
    u.h[2] = __float2bfloat16(v0.z);
    u.h[3] = __float2bfloat16(v0.w);
    u.h[4] = __float2bfloat16(v1.x);
    u.h[5] = __float2bfloat16(v1.y);
    u.h[6] = __float2bfloat16(v1.z);
    u.h[7] = __float2bfloat16(v1.w);
    *(bf16x8*)(w_bf + i) = u.v;
}

// ---------------- kernel 3: attn = softmax(l2n(q) @ l2n(k_c) * scale) ----------------
__global__ __launch_bounds__(256)
void attn_kernel(const float* __restrict__ q_part, const float* __restrict__ k_c,
                 float* __restrict__ attn) {
    const float SCALE = 0.03608439182435161f;  // 768^-0.5
    int b = blockIdx.x, t = threadIdx.x;
    __shared__ float qs[NC];
    __shared__ float red[256];
    __shared__ float pd[4][NCEN];
    __shared__ float pk[4][NCEN];

    const size_t PS = (size_t)NB * NC;
    for (int i = t; i < NC; i += 256) {
        size_t idx = (size_t)b * NC + i;
        float acc = 0.f;
#pragma unroll
        for (int p = 0; p < QPARTS; ++p) acc += q_part[p * PS + idx];
        qs[i] = acc * (1.0f / (float)NN);
    }
    __syncthreads();

    float s = 0.f;
    for (int i = t; i < NC; i += 256) { float v = qs[i]; s += v * v; }
    red[t] = s;
    __syncthreads();
    for (int o = 128; o > 0; o >>= 1) {
        if (t < o) red[t] += red[t + o];
        __syncthreads();
    }
    float qn = sqrtf(red[0]);

    int j = t & 63, part = t >> 6;
    float d = 0.f, kk = 0.f;
    int c0 = part * 192;
    for (int c = c0; c < c0 + 192; ++c) {
        float kv = k_c[c * NCEN + j];
        d += kv * qs[c];
        kk += kv * kv;
    }
    pd[part][j] = d;
    pk[part][j] = kk;
    __syncthreads();

    if (t < NCEN) {
        float dot = pd[0][t] + pd[1][t] + pd[2][t] + pd[3][t];
        float kn  = sqrtf(pk[0][t] + pk[1][t] + pk[2][t] + pk[3][t]);
        float lg = dot / (fmaxf(qn, 1e-12f) * fmaxf(kn, 1e-12f)) * SCALE;
        float mx = lg;
        for (int o = 32; o > 0; o >>= 1) mx = fmaxf(mx, __shfl_xor(mx, o, 64));
        float e = expf(lg - mx);
        float sum = e;
        for (int o = 32; o > 0; o >>= 1) sum += __shfl_xor(sum, o, 64);
        attn[b * NCEN + t] = e / sum;
    }
}

// ------- kernel 4: v_pad[b,n,m] = sum_c attn[b,c] v_c[c,n,m]; grid (RPAD, NB/BGRP) -------
__global__ __launch_bounds__(256)
void mix_kernel(const float* __restrict__ attn, const float* __restrict__ v_c,
                __hip_bfloat16* __restrict__ v_pad) {
    int n = blockIdx.x;   // 0..255
    int g = blockIdx.y;   // 0..3
    int m = threadIdx.x;  // 0..255

    __shared__ float sattn[BGRP][NCEN];
    for (int i = threadIdx.x; i < BGRP * NCEN; i += 256)
        sattn[i >> 6][i & 63] = attn[(g * BGRP + (i >> 6)) * NCEN + (i & 63)];
    __syncthreads();

    __hip_bfloat16 z = __float2bfloat16(0.f);
    size_t base = (size_t)n * KPAD + m;
    if (n >= NN || m >= NN) {
#pragma unroll
        for (int bb = 0; bb < BGRP; ++bb)
            v_pad[(size_t)(g * BGRP + bb) * RPAD * KPAD + base] = z;
        return;
    }
    float vc[NCEN];
    const float* vp = v_c + (size_t)n * NN + m;
#pragma unroll
    for (int c = 0; c < NCEN; ++c) vc[c] = vp[(size_t)c * NN * NN];
#pragma unroll
    for (int bb = 0; bb < BGRP; ++bb) {
        float acc = 0.f;
#pragma unroll
        for (int c = 0; c < NCEN; ++c) acc += sattn[bb][c] * vc[c];
        v_pad[(size_t)(g * BGRP + bb) * RPAD * KPAD + base] = __float2bfloat16(acc);
    }
}

// ================= pipelined 256x256 NT GEMM, 8 waves, BK=32, 4-slot LDS ring ==========
// C[row,col] = sum_k A[row,k]*B[col,k] (+bias[col]). Per batch bb (grid 3*NB, XCD-grouped).
// LDS layout (shorts): A slots [0,32768): slot s at s*8192, row r at +r*32 (64B rows).
//                      B slots [32768,65536): same shape. Total 128 KB.
// Swizzle: LDS[row][chunk] holds global 16B-chunk (chunk ^ ((row>>2)&3)).
//   staging: lane l writes LDS linearly (row=base+(l>>2), chunk=l&3), global src
//   chunk = (l&3) ^ ((l>>4)&3)  [since (row>>2)&3 == (l>>4)&3 for 16-row wave slices]
//   ds_read: frag (row = *+lrow, want k-chunk=quad) reads chunk quad ^ ((lrow>>2)&3).
//   -> each 16-lane group covers all 8 four-bank groups exactly twice: 2-way floor.

template <int SLOT, bool STG, int VMN>
__device__ __forceinline__ void kstep(unsigned short* ldsw, int t,
                                      const unsigned short* gA0, const unsigned short* gA1,
                                      const unsigned short* gB0, const unsigned short* gB1,
                                      int aW0, int aW1, int aR, int bR,
                                      f32x4 (&acc)[8][4]) {
    constexpr int S3 = (SLOT + 3) & 3;
    // ---- phase A: stage A(t+3), read B-frags + A-frags 0..3, 16 MFMA ----
    __builtin_amdgcn_sched_barrier(0);
    if constexpr (STG) {
        size_t ko = (size_t)(t + 3) * 32;
        async_copy16(gA0 + ko, ldsw + S3 * 8192 + aW0);
        async_copy16(gA1 + ko, ldsw + S3 * 8192 + aW1);
    }
    bf16x8 af[4], bfr[4];
#pragma unroll
    for (int n = 0; n < 4; ++n)
        bfr[n] = *(const bf16x8*)(ldsw + 32768 + SLOT * 8192 + bR + n * 512);
#pragma unroll
    for (int m = 0; m < 4; ++m)
        af[m] = *(const bf16x8*)(ldsw + SLOT * 8192 + aR + m * 512);
    __builtin_amdgcn_sched_barrier(0);
    __builtin_amdgcn_s_barrier();
    __builtin_amdgcn_s_setprio(1);
#pragma unroll
    for (int m = 0; m < 4; ++m)
#pragma unroll
        for (int n = 0; n < 4; ++n)
            acc[m][n] = __builtin_amdgcn_mfma_f32_16x16x32_bf16(af[m], bfr[n], acc[m][n], 0, 0, 0);
    __builtin_amdgcn_s_setprio(0);
    __builtin_amdgcn_sched_barrier(0);
    __builtin_amdgcn_s_barrier();
    // ---- phase B: stage B(t+3), read A-frags 4..7, 16 MFMA ----
    if constexpr (STG) {
        size_t ko = (size_t)(t + 3) * 32;
        async_copy16(gB0 + ko, ldsw + 32768 + S3 * 8192 + aW0);
        async_copy16(gB1 + ko, ldsw + 32768 + S3 * 8192 + aW1);
    }
#pragma unroll
    for (int m = 0; m < 4; ++m)
        af[m] = *(const bf16x8*)(ldsw + SLOT * 8192 + aR + (4 + m) * 512);
    __builtin_amdgcn_sched_barrier(0);
    __builtin_amdgcn_s_barrier();
    __builtin_amdgcn_s_setprio(1);
#pragma unroll
    for (int m = 0; m < 4; ++m)
#pragma unroll
        for (int n = 0; n < 4; ++n)
            acc[4 + m][n] = __builtin_amdgcn_mfma_f32_16x16x32_bf16(af[m], bfr[n], acc[4 + m][n], 0, 0, 0);
    __builtin_amdgcn_s_setprio(0);
    __builtin_amdgcn_sched_barrier(0);
    // tile boundary: guarantee tile t+1 landed before any wave reads it next step.
    if constexpr (VMN >= 0)
        asm volatile("s_waitcnt vmcnt(%0)" :: "i"(VMN) : "memory");
    __builtin_amdgcn_s_barrier();
    asm volatile("" ::: "memory");
}

// TK = K/32 K-tiles (must be %4==0). TILE_N: grid tile indexes N (else M).
template <int TK, bool OUT_BF16, bool TILE_N>
__global__ __launch_bounds__(512, 2)
void gemm_nt8(const __hip_bfloat16* __restrict__ A, size_t strideA,
              const __hip_bfloat16* __restrict__ Bm, size_t strideB,
              void* __restrict__ Cout, size_t strideC,
              const float* __restrict__ bias,
              int lda, int ldb, int ldc, int Mstore) {
    __shared__ __align__(16) unsigned short ldsw[65536];  // 128 KB

    // XCD-grouped bijective swizzle: all 3 tile-blocks of a batch share one XCD.
    int L = blockIdx.x;
    int w = (L & 7) * ((int)gridDim.x >> 3) + (L >> 3);
    int bb = w / 3, tile = w - bb * 3;
    int bm = TILE_N ? 0 : tile, bn = TILE_N ? tile : 0;

    const unsigned short* Ab = (const unsigned short*)A + (size_t)bb * strideA + (size_t)(bm * 256) * lda;
    const unsigned short* Bb = (const unsigned short*)Bm + (size_t)bb * strideB + (size_t)(bn * 256) * ldb;

    int tid = threadIdx.x;
    int wid = tid >> 6, lane = tid & 63;
    int lrow = lane & 15, quad = lane >> 4;
    int wr = wid >> 2, wcn = wid & 3;  // wave covers rows [wr*128,+128) x cols [wcn*64,+64)

    // staging addresses (per-thread global, wave-uniform LDS)
    int srow = lane >> 2;
    int sch = 8 * ((lane & 3) ^ ((lane >> 4) & 3));  // swizzled 16B-chunk (elements)
    const unsigned short* gA0 = Ab + (size_t)(16 * wid + srow) * lda + sch;
    const unsigned short* gA1 = Ab + (size_t)(128 + 16 * wid + srow) * lda + sch;
    const unsigned short* gB0 = Bb + (size_t)(16 * wid + srow) * ldb + sch;
    const unsigned short* gB1 = Bb + (size_t)(128 + 16 * wid + srow) * ldb + sch;
    int aW0 = wid * 512;          // shorts; + slot*8192 (+32768 for B)
    int aW1 = 4096 + wid * 512;

    // ds_read bases (shorts)
    int rsw = 8 * (quad ^ (lrow >> 2));
    int aR = (wr * 128 + lrow) * 32 + rsw;
    int bR = (wcn * 64 + lrow) * 32 + rsw;

    f32x4 acc[8][4] = {};

    // prologue: stage tiles 0,1,2; tile 0 guaranteed landed (outstanding <= 8 = tiles 1,2)
#pragma unroll
    for (int t = 0; t < 3; ++t) {
        async_copy16(gA0 + t * 32, ldsw + t * 8192 + aW0);
        async_copy16(gA1 + t * 32, ldsw + t * 8192 + aW1);
        async_copy16(gB0 + t * 32, ldsw + 32768 + t * 8192 + aW0);
        async_copy16(gB1 + t * 32, ldsw + 32768 + t * 8192 + aW1);
    }
    asm volatile("s_waitcnt vmcnt(8)" ::: "memory");
    __builtin_amdgcn_s_barrier();
    asm volatile("" ::: "memory");

    for (int tb = 0; tb < TK / 4 - 1; ++tb) {
        int t = tb * 4;
        kstep<0, true, 8>(ldsw, t + 0, gA0, gA1, gB0, gB1, aW0, aW1, aR, bR, acc);
        kstep<1, true, 8>(ldsw, t + 1, gA0, gA1, gB0, gB1, aW0, aW1, aR, bR, acc);
        kstep<2, true, 8>(ldsw, t + 2, gA0, gA1, gB0, gB1, aW0, aW1, aR, bR, acc);
        kstep<3, true, 8>(ldsw, t + 3, gA0, gA1, gB0, gB1, aW0, aW1, aR, bR, acc);
    }
    kstep<0, true,  8>(ldsw, TK - 4, gA0, gA1, gB0, gB1, aW0, aW1, aR, bR, acc);
    kstep<1, false, 4>(ldsw, TK - 3, gA0, gA1, gB0, gB1, aW0, aW1, aR, bR, acc);
    kstep<2, false, 0>(ldsw, TK - 2, gA0, gA1, gB0, gB1, aW0, aW1, aR, bR, acc);
    kstep<3, false, -1>(ldsw, TK - 1, gA0, gA1, gB0, gB1, aW0, aW1, aR, bR, acc);

    // epilogue: D[row=quad*4+r][col=lrow] per 16x16 tile (m89-verified mapping)
    size_t cbase = (size_t)bb * strideC;
#pragma unroll
    for (int mrep = 0; mrep < 8; ++mrep) {
        int row0 = bm * 256 + wr * 128 + mrep * 16 + quad * 4;
#pragma unroll
        for (int nrep = 0; nrep < 4; ++nrep) {
            int col = bn * 256 + wcn * 64 + nrep * 16 + lrow;
            float badd = bias ? bias[col] : 0.f;
#pragma unroll
            for (int r = 0; r < 4; ++r) {
                int row = row0 + r;
                if (row < Mstore) {
                    float v = acc[mrep][nrep][r] + badd;
                    if (OUT_BF16)
                        ((__hip_bfloat16*)Cout)[cbase + (size_t)row * ldc + col] = __float2bfloat16(v);
                    else
                        ((float*)Cout)[cbase + (size_t)row * ldc + col] = v;
                }
            }
        }
    }
}

extern "C" void kernel_launch(void* const* d_in, const int* in_sizes, int n_in,
                              void* d_out, int out_size, void* d_ws, size_t ws_size,
                              hipStream_t stream) {
    const float* x      = (const float*)d_in[0];  // (128,196,768)
    const float* k_c    = (const float*)d_in[1];  // (768,64)
    const float* v_c    = (const float*)d_in[2];  // (64,196,196)
    const float* proj_w = (const float*)d_in[3];  // (768,768)
    const float* proj_b = (const float*)d_in[4];  // (768,)
    float* out = (float*)d_out;                   // (128,196,768)

    char* ws = (char*)d_ws;
    size_t off = 0;
    auto alloc = [&](size_t bytes) {
        void* p = ws + off;
        off = (off + bytes + 255) & ~(size_t)255;
        return p;
    };
    __hip_bfloat16* x_bf  = (__hip_bfloat16*)alloc((size_t)NB * RPAD * NC * 2);   // 50.3 MB
    __hip_bfloat16* w_bf  = (__hip_bfloat16*)alloc((size_t)NC * NC * 2);          // 1.2 MB
    __hip_bfloat16* xp_t  = (__hip_bfloat16*)alloc((size_t)NB * NC * KPAD * 2);   // 50.3 MB
    __hip_bfloat16* v_pad = (__hip_bfloat16*)alloc((size_t)NB * RPAD * KPAD * 2); // 16.8 MB
    float* q_part = (float*)alloc((size_t)QPARTS * NB * NC * 4);                  // 2.75 MB
    float* attn   = (float*)alloc((size_t)NB * NCEN * 4);

    convert_x_kernel<<<dim3(NB, 7), 192, 0, stream>>>(x, x_bf, q_part);
    convert_w_kernel<<<dim3((NC * NC / 8 + 255) / 256), 256, 0, stream>>>(proj_w, w_bf);
    attn_kernel<<<dim3(NB), 256, 0, stream>>>(q_part, k_c, attn);
    mix_kernel<<<dim3(RPAD, NB / BGRP), 256, 0, stream>>>(attn, v_c, v_pad);

    // xp_t[b,d,m] = sum_k W[d,k] * x_bf[b,m,k]; M=768(d, 3 tiles), N=256(m), K=768
    gemm_nt8<24, true, false><<<dim3(3 * NB), 512, 0, stream>>>(
        w_bf, 0, x_bf, (size_t)RPAD * NC, xp_t, (size_t)NC * KPAD, nullptr,
        NC, NC, KPAD, NC);

    // out[b,n,d] = sum_m v_pad[b,n,m] * xp_t[b,d,m] + bias[d]; M=256(n), N=768(d, 3 tiles), K=256
    gemm_nt8<8, false, true><<<dim3(3 * NB), 512, 0, stream>>>(
        v_pad, (size_t)RPAD * KPAD, xp_t, (size_t)NC * KPAD, out, (size_t)NN * NC, proj_b,
        KPAD, KPAD, NC, NN);
}

// Round 3
// 310.432 us; speedup vs baseline: 1.0151x; 1.0151x over previous
//
#include <hip/hip_runtime.h>
#include <hip/hip_bf16.h>

// Problem: B=128, N=196, C=768, centers=64
//   q = mean_n x; attn = softmax(l2n(q)@l2n(k_c) * C^-0.5)
//   v = attn@v_c (B,N,N); out = (v @ x) @ W^T + b
// Reassociated: xp_t[b,d,m] = sum_k W[d,k] x[b,m,k]  (NT GEMM, output transposed)
//               out[b,n,d]  = sum_m v[b,n,m] xp_t[b,d,m] + bias[d] (NT GEMM)
// R6 (fixes to the R5 pipelined 256x256 kernel, diagnosed from counters):
//   - BANK-CONFLICT FIX: rows are 64B (BK=32) so bank-group = 16*(row&1)+4*chunk.
//     LDS issues ds_read_b128 ~8 lanes/cycle in lane order; the octet must cover
//     all 8 four-bank groups. swz(row) = (row>>1)&3 achieves this (R5's (row>>2)&3
//     gave 2-way octet collisions -> 3.54M conflicts). Stage side: global chunk
//     (l&3)^((l>>3)&3); read side: quad^((lrow>>1)&3).
//   - one dead s_barrier per kstep removed (4 -> 3; the MFMA-A/phase-B barrier
//     protected nothing: S3's previous readers joined at the prior tile boundary).
//   - ring-of-4 LDS slots + s_waitcnt vmcnt(8) per tile boundary kept (race-free:
//     each wave's own vmcnt retires its own tile-t+1 loads BEFORE the boundary
//     barrier; the barrier join makes that global).

#define NB   128
#define NN   196
#define NC   768
#define NCEN 64
#define RPAD 256   // padded row-dim for x_bf (m rows) and v_pad (n rows)
#define KPAD 256   // padded m index (K of gemm2, cols of xp_t)
#define BGRP 32    // batches per mix block
#define QPARTS 7

using bf16x8 = __attribute__((ext_vector_type(8))) short;
using f32x4  = __attribute__((ext_vector_type(4))) float;

__device__ __forceinline__ void async_copy16(const void* g, void* l) {
    // width=16: emits global_load_lds_dwordx4. LDS dest = wave-uniform base + lane*16.
    __builtin_amdgcn_global_load_lds((const __attribute__((address_space(1))) void*)g,
                                     (__attribute__((address_space(3))) void*)l, 16, 0, 0);
}

// ---- kernel 1: x -> bf16 (padded) + partial column sums; grid (NB, 7), block 192 ----
__global__ __launch_bounds__(192)
void convert_x_kernel(const float* __restrict__ x, __hip_bfloat16* __restrict__ x_bf,
                      float* __restrict__ q_part) {
    __shared__ float qsh[NC];
    int b = blockIdx.x, y = blockIdx.y, t = threadIdx.x;
    int cg = t % 96, rg = t / 96;
    int c = cg * 8;
    const float* xp = x + (size_t)b * NN * NC + c;
    __hip_bfloat16* xo = x_bf + (size_t)b * RPAD * NC + c;
    float s[8] = {0.f, 0.f, 0.f, 0.f, 0.f, 0.f, 0.f, 0.f};
    int m0 = y * 28 + rg * 14;
#pragma unroll 2
    for (int m = m0; m < m0 + 14; ++m) {
        const float* src = xp + (size_t)m * NC;
        float4 v0 = *(const float4*)src;
        float4 v1 = *(const float4*)(src + 4);
        union { bf16x8 v; __hip_bfloat16 h[8]; } u;
        u.h[0] = __float2bfloat16(v0.x); s[0] += v0.x;
        u.h[1] = __float2bfloat16(v0.y); s[1] += v0.y;
        u.h[2] = __float2bfloat16(v0.z); s[2] += v0.z;
        u.h[3] = __float2bfloat16(v0.w); s[3] += v0.w;
        u.h[4] = __float2bfloat16(v1.x); s[4] += v1.x;
        u.h[5] = __float2bfloat16(v1.y); s[5] += v1.y;
        u.h[6] = __float2bfloat16(v1.z); s[6] += v1.z;
        u.h[7] = __float2bfloat16(v1.w); s[7] += v1.w;
        *(bf16x8*)(xo + (size_t)m * NC) = u.v;
    }
    if (y == 6) {
        // zero rows 196..255: their xp_t columns feed gemm2's padded K range and
        // must be exact zeros (0 * 0, never NaN * 0).
        bf16x8 z = {};
        int mz0 = 196 + rg * 30;
        for (int m = mz0; m < mz0 + 30; ++m)
            *(bf16x8*)(xo + (size_t)m * NC) = z;
    }
    if (rg == 0) {
#pragma unroll
        for (int j = 0; j < 8; ++j) qsh[c + j] = s[j];
    }
    __syncthreads();
    if (rg == 1) {
        float* qp = q_part + ((size_t)y * NB + b) * NC + c;
        float4 o0 = make_float4(qsh[c] + s[0], qsh[c + 1] + s[1],
                                qsh[c + 2] + s[2], qsh[c + 3] + s[3]);
        float4 o1 = make_float4(qsh[c + 4] + s[4], qsh[c + 5] + s[5],
                                qsh[c + 6] + s[6], qsh[c + 7] + s[7]);
        *(float4*)qp = o0;
        *(float4*)(qp + 4) = o1;
    }
}

// ---------------- kernel 2: proj_w -> bf16 (vectorized) ----------------
__global__ __launch_bounds__(256)
void convert_w_kernel(const float* __restrict__ w, __hip_bfloat16* __restrict__ w_bf) {
    int i = (blockIdx.x * 256 + threadIdx.x) * 8;
    if (i >= NC * NC) return;
    float4 v0 = *(const float4*)(w + i);
    float4 v1 = *(const float4*)(w + i + 4);
    union { bf16x8 v; __hip_bfloat16 h[8]; } u;
    u.h[0] = __float2bfloat16(v0.x);
    u.h[1] = __float2bfloat16(v0.y);
    u.h[2] = __float2bfloat16(v0.z);
    u.h[3] = __float2bfloat16(v0.w);
    u.h[4] = __float2bfloat16(v1.x);
    u.h[5] = __float2bfloat16(v1.y);
    u.h[6] = __float2bfloat16(v1.z);
    u.h[7] = __float2bfloat16(v1.w);
    *(bf16x8*)(w_bf + i) = u.v;
}

// ---------------- kernel 3: attn = softmax(l2n(q) @ l2n(k_c) * scale) ----------------
__global__ __launch_bounds__(256)
void attn_kernel(const float* __restrict__ q_part, const float* __restrict__ k_c,
                 float* __restrict__ attn) {
    const float SCALE = 0.03608439182435161f;  // 768^-0.5
    int b = blockIdx.x, t = threadIdx.x;
    __shared__ float qs[NC];
    __shared__ float red[256];
    __shared__ float pd[4][NCEN];
    __shared__ float pk[4][NCEN];

    const size_t PS = (size_t)NB * NC;
    for (int i = t; i < NC; i += 256) {
        size_t idx = (size_t)b * NC + i;
        float acc = 0.f;
#pragma unroll
        for (int p = 0; p < QPARTS; ++p) acc += q_part[p * PS + idx];
        qs[i] = acc * (1.0f / (float)NN);
    }
    __syncthreads();

    float s = 0.f;
    for (int i = t; i < NC; i += 256) { float v = qs[i]; s += v * v; }
    red[t] = s;
    __syncthreads();
    for (int o = 128; o > 0; o >>= 1) {
        if (t < o) red[t] += red[t + o];
        __syncthreads();
    }
    float qn = sqrtf(red[0]);

    int j = t & 63, part = t >> 6;
    float d = 0.f, kk = 0.f;
    int c0 = part * 192;
    for (int c = c0; c < c0 + 192; ++c) {
        float kv = k_c[c * NCEN + j];
        d += kv * qs[c];
        kk += kv * kv;
    }
    pd[part][j] = d;
    pk[part][j] = kk;
    __syncthreads();

    if (t < NCEN) {
        float dot = pd[0][t] + pd[1][t] + pd[2][t] + pd[3][t];
        float kn  = sqrtf(pk[0][t] + pk[1][t] + pk[2][t] + pk[3][t]);
        float lg = dot / (fmaxf(qn, 1e-12f) * fmaxf(kn, 1e-12f)) * SCALE;
        float mx = lg;
        for (int o = 32; o > 0; o >>= 1) mx = fmaxf(mx, __shfl_xor(mx, o, 64));
        float e = expf(lg - mx);
        float sum = e;
        for (int o = 32; o > 0; o >>= 1) sum += __shfl_xor(sum, o, 64);
        attn[b * NCEN + t] = e / sum;
    }
}

// ------- kernel 4: v_pad[b,n,m] = sum_c attn[b,c] v_c[c,n,m]; grid (RPAD, NB/BGRP) -------
__global__ __launch_bounds__(256)
void mix_kernel(const float* __restrict__ attn, const float* __restrict__ v_c,
                __hip_bfloat16* __restrict__ v_pad) {
    int n = blockIdx.x;   // 0..255
    int g = blockIdx.y;   // 0..3
    int m = threadIdx.x;  // 0..255

    __shared__ float sattn[BGRP][NCEN];
    for (int i = threadIdx.x; i < BGRP * NCEN; i += 256)
        sattn[i >> 6][i & 63] = attn[(g * BGRP + (i >> 6)) * NCEN + (i & 63)];
    __syncthreads();

    __hip_bfloat16 z = __float2bfloat16(0.f);
    size_t base = (size_t)n * KPAD + m;
    if (n >= NN || m >= NN) {
#pragma unroll
        for (int bb = 0; bb < BGRP; ++bb)
            v_pad[(size_t)(g * BGRP + bb) * RPAD * KPAD + base] = z;
        return;
    }
    float vc[NCEN];
    const float* vp = v_c + (size_t)n * NN + m;
#pragma unroll
    for (int c = 0; c < NCEN; ++c) vc[c] = vp[(size_t)c * NN * NN];
#pragma unroll
    for (int bb = 0; bb < BGRP; ++bb) {
        float acc = 0.f;
#pragma unroll
        for (int c = 0; c < NCEN; ++c) acc += sattn[bb][c] * vc[c];
        v_pad[(size_t)(g * BGRP + bb) * RPAD * KPAD + base] = __float2bfloat16(acc);
    }
}

// ================= pipelined 256x256 NT GEMM, 8 waves, BK=32, 4-slot LDS ring ==========
// C[row,col] = sum_k A[row,k]*B[col,k] (+bias[col]). Per batch bb (grid 3*NB, XCD-grouped).
// LDS (shorts): A slots [0,32768): slot s at s*8192, row r at +r*32 (64B rows).
//               B slots [32768,65536): same. Total 128 KB.
// Swizzle (R6): LDS[row][phys chunk] holds global chunk (phys ^ ((row>>1)&3)).
//   stage: lane l writes LDS linearly (row=base16+(l>>2), phys=l&3); global chunk
//          = (l&3) ^ ((l>>3)&3)   [(row>>1)&3 == (l>>3)&3 for 16-row-aligned bases]
//   read:  frag row base+lrow needs logical chunk quad -> phys = quad^((lrow>>1)&3).
//   octet check (lanes lrow 0..7, any quad): bank group 4*(lrow&1) + phys covers
//   all 8 four-bank groups exactly once -> conflict-free ds_read_b128.

template <int SLOT, bool STG, int VMN>
__device__ __forceinline__ void kstep(unsigned short* ldsw, int t,
                                      const unsigned short* gA0, const unsigned short* gA1,
                                      const unsigned short* gB0, const unsigned short* gB1,
                                      int aW0, int aW1, int aR, int bR,
                                      f32x4 (&acc)[8][4]) {
    constexpr int S3 = (SLOT + 3) & 3;
    // ---- phase A: stage A(t+3), read B-frags + A-frags 0..3, 16 MFMA ----
    __builtin_amdgcn_sched_barrier(0);
    if constexpr (STG) {
        size_t ko = (size_t)(t + 3) * 32;
        async_copy16(gA0 + ko, ldsw + S3 * 8192 + aW0);
        async_copy16(gA1 + ko, ldsw + S3 * 8192 + aW1);
    }
    bf16x8 af[4], bfr[4];
#pragma unroll
    for (int n = 0; n < 4; ++n)
        bfr[n] = *(const bf16x8*)(ldsw + 32768 + SLOT * 8192 + bR + n * 512);
#pragma unroll
    for (int m = 0; m < 4; ++m)
        af[m] = *(const bf16x8*)(ldsw + SLOT * 8192 + aR + m * 512);
    __builtin_amdgcn_sched_barrier(0);
    __builtin_amdgcn_s_barrier();
    __builtin_amdgcn_s_setprio(1);
#pragma unroll
    for (int m = 0; m < 4; ++m)
#pragma unroll
        for (int n = 0; n < 4; ++n)
            acc[m][n] = __builtin_amdgcn_mfma_f32_16x16x32_bf16(af[m], bfr[n], acc[m][n], 0, 0, 0);
    __builtin_amdgcn_s_setprio(0);
    __builtin_amdgcn_sched_barrier(0);
    // ---- phase B: stage B(t+3), read A-frags 4..7, 16 MFMA (no barrier needed
    //      between the MFMA-A cluster and these ds_reads: same slot, already live) ----
    if constexpr (STG) {
        size_t ko = (size_t)(t + 3) * 32;
        async_copy16(gB0 + ko, ldsw + 32768 + S3 * 8192 + aW0);
        async_copy16(gB1 + ko, ldsw + 32768 + S3 * 8192 + aW1);
    }
#pragma unroll
    for (int m = 0; m < 4; ++m)
        af[m] = *(const bf16x8*)(ldsw + SLOT * 8192 + aR + (4 + m) * 512);
    __builtin_amdgcn_sched_barrier(0);
    __builtin_amdgcn_s_barrier();
    __builtin_amdgcn_s_setprio(1);
#pragma unroll
    for (int m = 0; m < 4; ++m)
#pragma unroll
        for (int n = 0; n < 4; ++n)
            acc[4 + m][n] = __builtin_amdgcn_mfma_f32_16x16x32_bf16(af[m], bfr[n], acc[4 + m][n], 0, 0, 0);
    __builtin_amdgcn_s_setprio(0);
    __builtin_amdgcn_sched_barrier(0);
    // tile boundary: each wave retires its OWN tile-t+1 loads (vmcnt), then the
    // barrier join makes tile t+1 globally visible for the next kstep.
    if constexpr (VMN >= 0)
        asm volatile("s_waitcnt vmcnt(%0)" :: "i"(VMN) : "memory");
    __builtin_amdgcn_s_barrier();
    asm volatile("" ::: "memory");
}

// TK = K/32 K-tiles (must be %4==0). TILE_N: grid tile indexes N (else M).
template <int TK, bool OUT_BF16, bool TILE_N>
__global__ __launch_bounds__(512, 2)
void gemm_nt8(const __hip_bfloat16* __restrict__ A, size_t strideA,
              const __hip_bfloat16* __restrict__ Bm, size_t strideB,
              void* __restrict__ Cout, size_t strideC,
              const float* __restrict__ bias,
              int lda, int ldb, int ldc, int Mstore) {
    __shared__ __align__(16) unsigned short ldsw[65536];  // 128 KB

    // XCD-grouped bijective swizzle: all 3 tile-blocks of a batch share one XCD.
    int L = blockIdx.x;
    int w = (L & 7) * ((int)gridDim.x >> 3) + (L >> 3);
    int bb = w / 3, tile = w - bb * 3;
    int bm = TILE_N ? 0 : tile, bn = TILE_N ? tile : 0;

    const unsigned short* Ab = (const unsigned short*)A + (size_t)bb * strideA + (size_t)(bm * 256) * lda;
    const unsigned short* Bb = (const unsigned short*)Bm + (size_t)bb * strideB + (size_t)(bn * 256) * ldb;

    int tid = threadIdx.x;
    int wid = tid >> 6, lane = tid & 63;
    int lrow = lane & 15, quad = lane >> 4;
    int wr = wid >> 2, wcn = wid & 3;  // wave covers rows [wr*128,+128) x cols [wcn*64,+64)

    // staging addresses (per-thread global, wave-uniform LDS)
    int srow = lane >> 2;
    int sch = 8 * ((lane & 3) ^ ((lane >> 3) & 3));  // R6 swizzled 16B-chunk (elements)
    const unsigned short* gA0 = Ab + (size_t)(16 * wid + srow) * lda + sch;
    const unsigned short* gA1 = Ab + (size_t)(128 + 16 * wid + srow) * lda + sch;
    const unsigned short* gB0 = Bb + (size_t)(16 * wid + srow) * ldb + sch;
    const unsigned short* gB1 = Bb + (size_t)(128 + 16 * wid + srow) * ldb + sch;
    int aW0 = wid * 512;          // shorts; + slot*8192 (+32768 for B)
    int aW1 = 4096 + wid * 512;

    // ds_read bases (shorts): phys chunk = quad ^ ((lrow>>1)&3)
    int rsw = 8 * (quad ^ ((lrow >> 1) & 3));
    int aR = (wr * 128 + lrow) * 32 + rsw;
    int bR = (wcn * 64 + lrow) * 32 + rsw;

    f32x4 acc[8][4] = {};

    // prologue: stage tiles 0,1,2; own-wave vmcnt(8) -> own tile-0 loads done;
    // barrier join -> tile 0 globally landed.
#pragma unroll
    for (int t = 0; t < 3; ++t) {
        async_copy16(gA0 + t * 32, ldsw + t * 8192 + aW0);
        async_copy16(gA1 + t * 32, ldsw + t * 8192 + aW1);
        async_copy16(gB0 + t * 32, ldsw + 32768 + t * 8192 + aW0);
        async_copy16(gB1 + t * 32, ldsw + 32768 + t * 8192 + aW1);
    }
    asm volatile("s_waitcnt vmcnt(8)" ::: "memory");
    __builtin_amdgcn_s_barrier();
    asm volatile("" ::: "memory");

    for (int tb = 0; tb < TK / 4 - 1; ++tb) {
        int t = tb * 4;
        kstep<0, true, 8>(ldsw, t + 0, gA0, gA1, gB0, gB1, aW0, aW1, aR, bR, acc);
        kstep<1, true, 8>(ldsw, t + 1, gA0, gA1, gB0, gB1, aW0, aW1, aR, bR, acc);
        kstep<2, true, 8>(ldsw, t + 2, gA0, gA1, gB0, gB1, aW0, aW1, aR, bR, acc);
        kstep<3, true, 8>(ldsw, t + 3, gA0, gA1, gB0, gB1, aW0, aW1, aR, bR, acc);
    }
    kstep<0, true,  8>(ldsw, TK - 4, gA0, gA1, gB0, gB1, aW0, aW1, aR, bR, acc);
    kstep<1, false, 4>(ldsw, TK - 3, gA0, gA1, gB0, gB1, aW0, aW1, aR, bR, acc);
    kstep<2, false, 0>(ldsw, TK - 2, gA0, gA1, gB0, gB1, aW0, aW1, aR, bR, acc);
    kstep<3, false, -1>(ldsw, TK - 1, gA0, gA1, gB0, gB1, aW0, aW1, aR, bR, acc);

    // epilogue: D[row=quad*4+r][col=lrow] per 16x16 tile (m89-verified mapping)
    size_t cbase = (size_t)bb * strideC;
#pragma unroll
    for (int mrep = 0; mrep < 8; ++mrep) {
        int row0 = bm * 256 + wr * 128 + mrep * 16 + quad * 4;
#pragma unroll
        for (int nrep = 0; nrep < 4; ++nrep) {
            int col = bn * 256 + wcn * 64 + nrep * 16 + lrow;
            float badd = bias ? bias[col] : 0.f;
#pragma unroll
            for (int r = 0; r < 4; ++r) {
                int row = row0 + r;
                if (row < Mstore) {
                    float v = acc[mrep][nrep][r] + badd;
                    if (OUT_BF16)
                        ((__hip_bfloat16*)Cout)[cbase + (size_t)row * ldc + col] = __float2bfloat16(v);
                    else
                        ((float*)Cout)[cbase + (size_t)row * ldc + col] = v;
                }
            }
        }
    }
}

extern "C" void kernel_launch(void* const* d_in, const int* in_sizes, int n_in,
                              void* d_out, int out_size, void* d_ws, size_t ws_size,
                              hipStream_t stream) {
    const float* x      = (const float*)d_in[0];  // (128,196,768)
    const float* k_c    = (const float*)d_in[1];  // (768,64)
    const float* v_c    = (const float*)d_in[2];  // (64,196,196)
    const float* proj_w = (const float*)d_in[3];  // (768,768)
    const float* proj_b = (const float*)d_in[4];  // (768,)
    float* out = (float*)d_out;                   // (128,196,768)

    char* ws = (char*)d_ws;
    size_t off = 0;
    auto alloc = [&](size_t bytes) {
        void* p = ws + off;
        off = (off + bytes + 255) & ~(size_t)255;
        return p;
    };
    __hip_bfloat16* x_bf  = (__hip_bfloat16*)alloc((size_t)NB * RPAD * NC * 2);   // 50.3 MB
    __hip_bfloat16* w_bf  = (__hip_bfloat16*)alloc((size_t)NC * NC * 2);          // 1.2 MB
    __hip_bfloat16* xp_t  = (__hip_bfloat16*)alloc((size_t)NB * NC * KPAD * 2);   // 50.3 MB
    __hip_bfloat16* v_pad = (__hip_bfloat16*)alloc((size_t)NB * RPAD * KPAD * 2); // 16.8 MB
    float* q_part = (float*)alloc((size_t)QPARTS * NB * NC * 4);                  // 2.75 MB
    float* attn   = (float*)alloc((size_t)NB * NCEN * 4);

    convert_x_kernel<<<dim3(NB, 7), 192, 0, stream>>>(x, x_bf, q_part);
    convert_w_kernel<<<dim3((NC * NC / 8 + 255) / 256), 256, 0, stream>>>(proj_w, w_bf);
    attn_kernel<<<dim3(NB), 256, 0, stream>>>(q_part, k_c, attn);
    mix_kernel<<<dim3(RPAD, NB / BGRP), 256, 0, stream>>>(attn, v_c, v_pad);

    // xp_t[b,d,m] = sum_k W[d,k] * x_bf[b,m,k]; M=768(d, 3 tiles), N=256(m), K=768
    gemm_nt8<24, true, false><<<dim3(3 * NB), 512, 0, stream>>>(
        w_bf, 0, x_bf, (size_t)RPAD * NC, xp_t, (size_t)NC * KPAD, nullptr,
        NC, NC, KPAD, NC);

    // out[b,n,d] = sum_m v_pad[b,n,m] * xp_t[b,d,m] + bias[d]; M=256(n), N=768(d, 3 tiles), K=256
    gemm_nt8<8, false, true><<<dim3(3 * NB), 512, 0, stream>>>(
        v_pad, (size_t)RPAD * KPAD, xp_t, (size_t)NC * KPAD, out, (size_t)NN * NC, proj_b,
        KPAD, KPAD, NC, NN);
}